// Round 6
// baseline (138.888 us; speedup 1.0000x reference)
//
#include <hip/hip_runtime.h>
#include <math.h>

#define NTOK 100
#define EDIM 5
#define NH   4
#define NL   3
#define DD   64
#define BLK  64

// single-instruction transcendentals (1-ulp class; tolerance is 2^-7;
// fexp2/frcp/frsq already HW-validated in rounds 3-5)
__device__ __forceinline__ float fexp2(float x){ float r; asm("v_exp_f32 %0, %1" : "=v"(r) : "v"(x)); return r; }
__device__ __forceinline__ float frcp (float x){ float r; asm("v_rcp_f32 %0, %1" : "=v"(r) : "v"(x)); return r; }
__device__ __forceinline__ float frsq (float x){ float r; asm("v_rsq_f32 %0, %1" : "=v"(r) : "v"(x)); return r; }
// wave-uniform register broadcast (lane index provably uniform)
#define RL(v, l) __int_as_float(__builtin_amdgcn_readlane(__float_as_int(v), (l)))

// ---------------------------------------------------------------------------
// Kernel 1: fold per-head projections into 5x5 matrices.
//   M[l][h] = (1/8)*log2(e) * Wq^T Wk    (softmax uses native v_exp_f32)
//   P[l][h] = Wv^T Wo_h^T
// ws layout: float [2][NL][NH][EDIM][8]
// ---------------------------------------------------------------------------
__global__ void precompute_mp(const float* __restrict__ Wq,
                              const float* __restrict__ Wk,
                              const float* __restrict__ Wv,
                              const float* __restrict__ Wo,
                              float* __restrict__ mp) {
  const int blk = blockIdx.x;            // 24 = which(2) * l(3) * h(4)
  const int which = blk / 12;
  const int rem = blk % 12;
  const int l = rem / 4, h = rem % 4;
  const int t = threadIdx.x;             // 64 threads

  __shared__ float A[320];               // [d*5+e]
  __shared__ float Bsh[320];             // which0: [d*5+f] ; which1: [f*64+d]

  const float* wa = (which ? Wv : Wq) + (l*NH + h)*DD*EDIM;
  for (int r = t; r < 320; r += 64) A[r] = wa[r];
  if (which == 0) {
    const float* wk = Wk + (l*NH + h)*DD*EDIM;
    for (int r = t; r < 320; r += 64) Bsh[r] = wk[r];
  } else {
    for (int r = t; r < 320; r += 64) {
      int f = r >> 6, d = r & 63;
      Bsh[r] = Wo[(l*EDIM + f)*(NH*DD) + h*DD + d];
    }
  }
  __syncthreads();
  if (t < 25) {
    int e = t / 5, f = t % 5;
    float acc = 0.f;
    if (which == 0) {
      #pragma unroll 8
      for (int d = 0; d < DD; ++d) acc += A[d*5+e] * Bsh[d*5+f];
      acc *= 0.125f * 1.44269504088896340736f;   // fold log2(e) for exp2
    } else {
      #pragma unroll 8
      for (int d = 0; d < DD; ++d) acc += A[d*5+e] * Bsh[f*64+d];
    }
    mp[which*960 + ((l*NH + h)*EDIM + e)*8 + f] = acc;
  }
}

// ---------------------------------------------------------------------------
// Kernel 2: ONE WAVE per batch element (BLK=64, grid=1024).
//   Lane i owns row i (slot A) and row i+64 (slot B, rare) in REGISTERS.
//   Each lane computes ALL 4 heads for its row -> the per-row attention
//   contribution c[5] is lane-local, so the token update (residual + LN +
//   FFN + LN) needs NO LDS, NO cross-wave exchange, NO barriers in the
//   layer loop.  o[j] broadcasts via v_readlane from the wave's own
//   registers (5 RLs amortized over 4 heads = 48 useful ops).
//   Rationale: r3-r5 showed wall pinned at ~52us while busy-time fell to
//   15.7us -- phase-locked waves stall together.  Independent waves make
//   stalls private; instruction stream is straight-line register code.
//   Rep row (index nm): a=0 so exp2(0)=1 -> uniform weights; correction
//   w += (100-nm)*o_rep; inv = 1/100.  Garbage lanes (>= rows) compute
//   safely (never read as keys j<nm, never written back).
// ---------------------------------------------------------------------------
__global__ __launch_bounds__(BLK, 1) void encoder_kernel(
    const float* __restrict__ x,
    const float* __restrict__ mp,
    const float* __restrict__ Wf,
    const float* __restrict__ bfv,
    const float* __restrict__ g1,
    const float* __restrict__ b1,
    const float* __restrict__ g2,
    const float* __restrict__ b2,
    float* __restrict__ out)
{
  const int b = blockIdx.x, ln = threadIdx.x;   // one wave: ln = lane

  __shared__ float4 s_MP4[480];            // 7680 B : M then P (broadcast reads)
  __shared__ float4 s_i4[104];             // staging / final state [0..3]
  __shared__ float  s_i1[104];             // state [4]
  __shared__ float  s_cf[152];             // Wf | bf | g1 | b1 | g2 | b2
  __shared__ int    s_cidx[NTOK];

  const float* mpf = (const float*)s_MP4;
  for (int r = ln; r < 480; r += 64) s_MP4[r] = ((const float4*)mp)[r];
  for (int r = ln; r < 104; r += 64) { s_i4[r] = make_float4(0.f,0.f,0.f,0.f); s_i1[r] = 0.f; }
  for (int r = ln; r < 150; r += 64) {
    float v;
    if      (r <  75) v = Wf[r];
    else if (r <  90) v = bfv[r-75];
    else if (r < 105) v = g1[r-90];
    else if (r < 120) v = b1[r-105];
    else if (r < 135) v = g2[r-120];
    else              v = b2[r-135];
    s_cf[r] = v;
  }
  __syncthreads();   // zero-init visible before scatter (cross-lane WAW)

  // ---- setup: tokens ln and ln+64; ballot compaction (all intra-wave) ----
  float kA0 = x[b*300 + 3*ln], kA1 = x[b*300 + 3*ln + 1], kA2 = x[b*300 + 3*ln + 2];
  bool mA = (kA2 > 0.f);
  float kB0 = 0.f, kB1 = 0.f, kB2 = 0.f; bool mB = false;
  if (ln < 36) {
    kB0 = x[b*300 + 192 + 3*ln]; kB1 = x[b*300 + 193 + 3*ln]; kB2 = x[b*300 + 194 + 3*ln];
    mB = (kB2 > 0.f);
  }
  unsigned long long bal0 = __ballot(mA);
  unsigned long long bal1 = __ballot(ln < 36 && mB);
  const int nm = __builtin_amdgcn_readfirstlane(__popcll(bal0) + __popcll(bal1));
  unsigned long long lm = (ln == 0) ? 0ull : ((1ull << ln) - 1ull);
  int preA = __popcll(bal0 & lm);
  int preB = __popcll(bal0) + __popcll(bal1 & lm);
  if (mA) {
    s_i4[preA] = make_float4(kA0, kA1, kA2, __sinf((float)ln));
    s_i1[preA] = __cosf((float)ln);
    s_cidx[ln] = preA;
  } else s_cidx[ln] = nm;
  if (ln < 36) {
    if (mB) {
      s_i4[preB] = make_float4(kB0, kB1, kB2, __sinf((float)(ln+64)));
      s_i1[preB] = __cosf((float)(ln+64));
      s_cidx[ln+64] = preB;
    } else s_cidx[ln+64] = nm;
  }
  __syncthreads();   // scatter visible before gather (cross-lane)

  const int rows = nm + 1;                  // includes rep token at index nm
  const bool twoRows = (rows > 64);         // uniform
  const int jhiA = (nm < 64) ? nm : 64;     // slot-A keys (j < 64)
  const float wext = (float)(NTOK - nm);

  // ---- register-resident token state ----
  float oA0,oA1,oA2,oA3,oA4, oB0,oB1,oB2,oB3,oB4;
  { float4 v = s_i4[ln]; oA0=v.x; oA1=v.y; oA2=v.z; oA3=v.w; oA4=s_i1[ln]; }
  if (twoRows && ln < 40) {
    float4 v = s_i4[ln+64]; oB0=v.x; oB1=v.y; oB2=v.z; oB3=v.w; oB4=s_i1[ln+64];
  } else { oB0=0.f; oB1=0.f; oB2=0.f; oB3=0.f; oB4=0.f; }

  for (int l = 0; l < NL; ++l) {
    const float* Mb = mpf + (l*NH*EDIM)*8;          // 4 heads' M: [(h*5+e)*8+f]
    const float* Pb = mpf + 960 + (l*NH*EDIM)*8;

    // ---- attention for one register-held row, ALL 4 heads ----
    auto attn_row = [&](float o0,float o1,float o2,float o3,float o4,
                        int row, float (&cS)[5]) {
      float oc[5] = {o0,o1,o2,o3,o4};
      float A[NH][5];
      #pragma unroll
      for (int h = 0; h < NH; ++h) {
        #pragma unroll
        for (int f = 0; f < 5; ++f) A[h][f] = 0.f;
        #pragma unroll
        for (int e = 0; e < 5; ++e) {
          const float* Mr = Mb + (h*5+e)*8;
          float4 m4 = *(const float4*)Mr; float m1 = Mr[4];
          float v = oc[e];
          A[h][0] += v*m4.x; A[h][1] += v*m4.y; A[h][2] += v*m4.z;
          A[h][3] += v*m4.w; A[h][4] += v*m1;
        }
      }
      const bool rep = (row == nm);
      if (rep) {
        #pragma unroll
        for (int h = 0; h < NH; ++h)
          { A[h][0]=0.f; A[h][1]=0.f; A[h][2]=0.f; A[h][3]=0.f; A[h][4]=0.f; }
      }
      float W[NH][5], LS[NH];
      #pragma unroll
      for (int h = 0; h < NH; ++h) {
        LS[h]=0.f; W[h][0]=0.f; W[h][1]=0.f; W[h][2]=0.f; W[h][3]=0.f; W[h][4]=0.f;
      }
      #pragma unroll 2
      for (int j = 0; j < jhiA; ++j) {          // keys in slot A (j<64)
        float ox = RL(oA0,j), oy = RL(oA1,j), oz = RL(oA2,j),
              ow = RL(oA3,j), oe = RL(oA4,j);
        #pragma unroll
        for (int h = 0; h < NH; ++h) {          // 4 independent chains
          float s = (A[h][0]*ox + A[h][1]*oy) + ((A[h][2]*oz + A[h][3]*ow) + A[h][4]*oe);
          float p = fexp2(s);
          LS[h] += p;
          W[h][0] += p*ox; W[h][1] += p*oy; W[h][2] += p*oz;
          W[h][3] += p*ow; W[h][4] += p*oe;
        }
      }
      if (twoRows) {
        #pragma unroll 2
        for (int j = 64; j < nm; ++j) {         // keys in slot B (j>=64)
          int jl = j - 64;
          float ox = RL(oB0,jl), oy = RL(oB1,jl), oz = RL(oB2,jl),
                ow = RL(oB3,jl), oe = RL(oB4,jl);
          #pragma unroll
          for (int h = 0; h < NH; ++h) {
            float s = (A[h][0]*ox + A[h][1]*oy) + ((A[h][2]*oz + A[h][3]*ow) + A[h][4]*oe);
            float p = fexp2(s);
            LS[h] += p;
            W[h][0] += p*ox; W[h][1] += p*oy; W[h][2] += p*oz;
            W[h][3] += p*ow; W[h][4] += p*oe;
          }
        }
      }
      if (rep) {   // masked keys all carry the rep state
        #pragma unroll
        for (int h = 0; h < NH; ++h) {
          W[h][0] += wext*o0; W[h][1] += wext*o1; W[h][2] += wext*o2;
          W[h][3] += wext*o3; W[h][4] += wext*o4;
        }
      }
      // normalize + P-apply, summed over heads -> lane-local c[5]
      cS[0]=0.f; cS[1]=0.f; cS[2]=0.f; cS[3]=0.f; cS[4]=0.f;
      #pragma unroll
      for (int h = 0; h < NH; ++h) {
        float inv = rep ? 0.01f : frcp(LS[h]);
        #pragma unroll
        for (int e = 0; e < 5; ++e) {
          const float* Pr = Pb + (h*5+e)*8;
          float4 p4 = *(const float4*)Pr; float p1 = Pr[4];
          float we = W[h][e] * inv;
          cS[0] += we*p4.x; cS[1] += we*p4.y; cS[2] += we*p4.z;
          cS[3] += we*p4.w; cS[4] += we*p1;
        }
      }
    };

    // ---- token update: all lane-local, no LDS, no barrier ----
    auto upd = [&](float& p0,float& p1,float& p2,float& p3,float& p4,
                   const float (&cS)[5]) {
      float y0 = p0 + cS[0], y1 = p1 + cS[1], y2 = p2 + cS[2];
      float y3 = p3 + cS[3], y4 = p4 + cS[4];
      float yv[5] = {y0,y1,y2,y3,y4};
      float mu = 0.2f*(y0+y1+y2+y3+y4);
      float var = 0.f;
      #pragma unroll
      for (int e = 0; e < 5; ++e) { float d = yv[e]-mu; var += d*d; }
      float iv = frsq(var*0.2f + 1e-5f);
      float l1[5];
      #pragma unroll
      for (int e = 0; e < 5; ++e)
        l1[e] = (yv[e]-mu)*iv*s_cf[90+l*5+e] + s_cf[105+l*5+e];
      float r2[5];
      #pragma unroll
      for (int e = 0; e < 5; ++e) {
        float acc = s_cf[75+l*5+e];
        #pragma unroll
        for (int f = 0; f < 5; ++f) acc += l1[f]*s_cf[l*25+e*5+f];
        acc = acc > 0.f ? acc : 0.f;
        r2[e] = acc + l1[e];
      }
      float mu2 = 0.2f*(r2[0]+r2[1]+r2[2]+r2[3]+r2[4]);
      float var2 = 0.f;
      #pragma unroll
      for (int e = 0; e < 5; ++e) { float d = r2[e]-mu2; var2 += d*d; }
      float iv2 = frsq(var2*0.2f + 1e-5f);
      p0 = (r2[0]-mu2)*iv2*s_cf[120+l*5+0] + s_cf[135+l*5+0];
      p1 = (r2[1]-mu2)*iv2*s_cf[120+l*5+1] + s_cf[135+l*5+1];
      p2 = (r2[2]-mu2)*iv2*s_cf[120+l*5+2] + s_cf[135+l*5+2];
      p3 = (r2[3]-mu2)*iv2*s_cf[120+l*5+3] + s_cf[135+l*5+3];
      p4 = (r2[4]-mu2)*iv2*s_cf[120+l*5+4] + s_cf[135+l*5+4];
    };

    float cSA[5], cSB[5];
    attn_row(oA0,oA1,oA2,oA3,oA4, ln, cSA);
    if (twoRows) attn_row(oB0,oB1,oB2,oB3,oB4, ln+64, cSB);
    // all key-reads done (sequential within the single wave) -> safe to update
    upd(oA0,oA1,oA2,oA3,oA4, cSA);
    if (twoRows) upd(oB0,oB1,oB2,oB3,oB4, cSB);
  }

  // ---- writeback: registers -> LDS, expand to [N,E] ----
  if (ln < rows) { s_i4[ln] = make_float4(oA0,oA1,oA2,oA3); s_i1[ln] = oA4; }
  if (twoRows && (ln + 64 < rows)) {
    s_i4[ln+64] = make_float4(oB0,oB1,oB2,oB3); s_i1[ln+64] = oB4;
  }
  __syncthreads();
  for (int r = ln; r < NTOK*EDIM; r += 64) {
    int i = r / EDIM;
    int e = r - i*EDIM;
    int c = s_cidx[i];
    float v = (e < 4) ? ((const float*)&s_i4[c])[e] : s_i1[c];
    out[b*(NTOK*EDIM) + r] = v;
  }
}

extern "C" void kernel_launch(void* const* d_in, const int* in_sizes, int n_in,
                              void* d_out, int out_size, void* d_ws, size_t ws_size,
                              hipStream_t stream) {
  const float* x  = (const float*)d_in[0];
  const float* Wq = (const float*)d_in[1];
  const float* Wk = (const float*)d_in[2];
  const float* Wv = (const float*)d_in[3];
  const float* Wo = (const float*)d_in[4];
  const float* Wf = (const float*)d_in[5];
  const float* bf = (const float*)d_in[6];
  const float* g1 = (const float*)d_in[7];
  const float* b1 = (const float*)d_in[8];
  const float* g2 = (const float*)d_in[9];
  const float* b2 = (const float*)d_in[10];
  float* outp = (float*)d_out;
  float* mp   = (float*)d_ws;   // 1920 floats

  precompute_mp<<<24, 64, 0, stream>>>(Wq, Wk, Wv, Wo, mp);
  encoder_kernel<<<1024, BLK, 0, stream>>>(x, mp, Wf, bf, g1, b1, g2, b2, outp);
}

// Round 7
// 116.553 us; speedup vs baseline: 1.1916x; 1.1916x over previous
//
#include <hip/hip_runtime.h>
#include <math.h>

#define NTOK 100
#define EDIM 5
#define NH   4
#define NL   3
#define DD   64
#define BLK  256

// single-instruction transcendentals (1-ulp class; tolerance is 2^-7;
// HW-validated rounds 3-6)
__device__ __forceinline__ float fexp2(float x){ float r; asm("v_exp_f32 %0, %1" : "=v"(r) : "v"(x)); return r; }
__device__ __forceinline__ float frcp (float x){ float r; asm("v_rcp_f32 %0, %1" : "=v"(r) : "v"(x)); return r; }
__device__ __forceinline__ float frsq (float x){ float r; asm("v_rsq_f32 %0, %1" : "=v"(r) : "v"(x)); return r; }

// ---------------------------------------------------------------------------
// Kernel 1: fold per-head projections into 5x5 matrices.
//   M[l][h] = (1/8)*log2(e) * Wq^T Wk    (softmax uses native v_exp_f32)
//   P[l][h] = Wv^T Wo_h^T
// ws layout: float [2][NL][NH][EDIM][8]
// ---------------------------------------------------------------------------
__global__ void precompute_mp(const float* __restrict__ Wq,
                              const float* __restrict__ Wk,
                              const float* __restrict__ Wv,
                              const float* __restrict__ Wo,
                              float* __restrict__ mp) {
  const int blk = blockIdx.x;            // 24 = which(2) * l(3) * h(4)
  const int which = blk / 12;
  const int rem = blk % 12;
  const int l = rem / 4, h = rem % 4;
  const int t = threadIdx.x;             // 64 threads

  __shared__ float A[320];               // [d*5+e]
  __shared__ float Bsh[320];             // which0: [d*5+f] ; which1: [f*64+d]

  const float* wa = (which ? Wv : Wq) + (l*NH + h)*DD*EDIM;
  for (int r = t; r < 320; r += 64) A[r] = wa[r];
  if (which == 0) {
    const float* wk = Wk + (l*NH + h)*DD*EDIM;
    for (int r = t; r < 320; r += 64) Bsh[r] = wk[r];
  } else {
    for (int r = t; r < 320; r += 64) {
      int f = r >> 6, d = r & 63;
      Bsh[r] = Wo[(l*EDIM + f)*(NH*DD) + h*DD + d];
    }
  }
  __syncthreads();
  if (t < 25) {
    int e = t / 5, f = t % 5;
    float acc = 0.f;
    if (which == 0) {
      #pragma unroll 8
      for (int d = 0; d < DD; ++d) acc += A[d*5+e] * Bsh[d*5+f];
      acc *= 0.125f * 1.44269504088896340736f;   // fold log2(e) for exp2
    } else {
      #pragma unroll 8
      for (int d = 0; d < DD; ++d) acc += A[d*5+e] * Bsh[f*64+d];
    }
    mp[which*960 + ((l*NH + h)*EDIM + e)*8 + f] = acc;
  }
}

// ---------------------------------------------------------------------------
// Kernel 2: r0's PROVEN structure (256 thr = 4 waves/SIMD, LDS token state,
// 2 rows/thread, adaptive j-split, LDS-broadcast j-loop that pipelines under
// lgkmcnt) -- readlane variants (r3-r6) all lost to it.  Lean retrofit:
//   * log2(e) folded into M; rep row via a=0 (exp2(0)=1) -> no per-iter
//     select in the j-loop; rep correction w += (100-nm)*o_rep moved to the
//     attention phase (g==0 only).
//   * native v_exp/v_rcp/v_rsq single instructions.
//   * readfirstlane(nm): all bounds/indices provably uniform.
//   * P-apply moved INTO the dense attention phase (wp = w @ P stored
//     unnormalized + ls); thin token pass per head is now 5 FMA + rcp.
//   * LN/FFN constants staged once into LDS (s_cf).
// ---------------------------------------------------------------------------
__global__ __launch_bounds__(BLK, 4) void encoder_kernel(
    const float* __restrict__ x,
    const float* __restrict__ mp,
    const float* __restrict__ Wf,
    const float* __restrict__ bfv,
    const float* __restrict__ g1,
    const float* __restrict__ b1,
    const float* __restrict__ g2,
    const float* __restrict__ b2,
    float* __restrict__ out)
{
  const int b = blockIdx.x, t = threadIdx.x;

  __shared__ float4 s_MP4[480];             // 7680 B: M then P
  __shared__ float4 s_o4[NTOK+2];           // token state [0..3]
  __shared__ float  s_o1[NTOK+2];           // token state [4]
  __shared__ float4 s_w4[2][NH][NTOK+2];    // wp[0..3] per (jgroup,h,i)
  __shared__ float2 s_w2[2][NH][NTOK+2];    // {wp[4], ls}
  __shared__ float  s_cf[152];              // Wf | bf | g1 | b1 | g2 | b2
  __shared__ int    s_cidx[NTOK];
  __shared__ unsigned long long s_bal[2];

  const float* mpf = (const float*)s_MP4;

  for (int r = t; r < 480; r += BLK) s_MP4[r] = ((const float4*)mp)[r];
  for (int r = t; r < 150; r += BLK) {
    float v;
    if      (r <  75) v = Wf[r];
    else if (r <  90) v = bfv[r-75];
    else if (r < 105) v = g1[r-90];
    else if (r < 120) v = b1[r-105];
    else if (r < 135) v = g2[r-120];
    else              v = b2[r-135];
    s_cf[r] = v;
  }

  // ---- setup: mask + ballot-based compaction ----
  float k0=0.f, k1=0.f, k2=0.f, msk=0.f;
  if (t < NTOK) {
    k0 = x[b*300 + 3*t];
    k1 = x[b*300 + 3*t + 1];
    k2 = x[b*300 + 3*t + 2];
    msk = (k2 > 0.f) ? 1.f : 0.f;
  }
  unsigned long long bal = __ballot(t < NTOK && msk != 0.f);
  if (t == 0)  s_bal[0] = bal;
  if (t == 64) s_bal[1] = bal;
  __syncthreads();
  const unsigned long long bw0 = s_bal[0], bw1 = s_bal[1];
  // readfirstlane: nm (and all derived bounds) provably uniform
  const int nm = __builtin_amdgcn_readfirstlane(__popcll(bw0) + __popcll(bw1));
  if (t < NTOK) {
    int lane = t & 63;
    unsigned long long lm = (lane == 0) ? 0ull : ((1ull << lane) - 1ull);
    int pre = (t < 64) ? __popcll(bw0 & lm) : (__popcll(bw0) + __popcll(bw1 & lm));
    if (msk != 0.f) {
      s_o4[pre] = make_float4(k0, k1, k2, __sinf((float)t));
      s_o1[pre] = __cosf((float)t);
      s_cidx[t] = pre;
    } else {
      s_cidx[t] = nm;
    }
  }
  if (t == 0) {
    s_o4[nm]   = make_float4(0.f,0.f,0.f,0.f); s_o1[nm]   = 0.f;  // rep token
    s_o4[nm+1] = make_float4(0.f,0.f,0.f,0.f); s_o1[nm+1] = 0.f;
  }
  __syncthreads();

  // ---- static task mapping: 2 rows/thread, adaptive j-split (r0) ----
  const int hp   = (nm + 2) >> 1;          // pairs cover i in [0, nm]
  const int natt = NH * hp;                // threads per j-group (<=204)
  const int nsplit = (2*natt <= BLK) ? 2 : 1;
  const bool task = (t < natt*nsplit);
  int h = 0, i0 = 0, i1 = 0, i1r = 0, jlo = 0, jhi = 0;
  bool rep0 = false, rep1 = false, w1ok = false, corr = false;
  if (task) {
    int g  = t / natt;
    int tt = t - g*natt;
    h = tt / hp; i0 = tt - h*hp; i1 = i0 + hp;
    i1r = (i1 <= nm) ? i1 : nm;
    w1ok = (i1 <= nm);
    rep0 = (i0 == nm); rep1 = (i1 == nm);
    corr = (g == 0);                       // rep-correction applied once
    int jmid = nm >> 1;
    if (nsplit == 2) { jlo = g ? jmid : 0; jhi = g ? nm : jmid; }
    else             { jlo = 0; jhi = nm; }
  }
  const int wg = task ? (t / natt) : 0;
  const float wext = (float)(NTOK - nm);

  for (int l = 0; l < NL; ++l) {
    if (task) {
      // a = o @ M_h for both rows (M rows shared between the two rows)
      const float* Mh = mpf + ((l*NH + h)*EDIM)*8;
      float4 oA = s_o4[i0];  float oA4 = s_o1[i0];
      float4 oB = s_o4[i1r]; float oB4 = s_o1[i1r];
      float oa[5] = {oA.x, oA.y, oA.z, oA.w, oA4};
      float ob[5] = {oB.x, oB.y, oB.z, oB.w, oB4};
      float a0[5], a1[5];
      #pragma unroll
      for (int f = 0; f < 5; ++f) { a0[f] = 0.f; a1[f] = 0.f; }
      #pragma unroll
      for (int e = 0; e < 5; ++e) {
        float4 mr = *(const float4*)(Mh + e*8); float m4 = Mh[e*8+4];
        float va = oa[e], vb = ob[e];
        a0[0] += va*mr.x; a0[1] += va*mr.y; a0[2] += va*mr.z; a0[3] += va*mr.w; a0[4] += va*m4;
        a1[0] += vb*mr.x; a1[1] += vb*mr.y; a1[2] += vb*mr.z; a1[3] += vb*mr.w; a1[4] += vb*m4;
      }
      if (rep0) { a0[0]=0.f; a0[1]=0.f; a0[2]=0.f; a0[3]=0.f; a0[4]=0.f; } // exp2(0)=1
      if (rep1) { a1[0]=0.f; a1[1]=0.f; a1[2]=0.f; a1[3]=0.f; a1[4]=0.f; }

      // attention j-loop: LDS broadcast reads (pipeline under lgkmcnt),
      // 2-row body, native exp2, no per-iter selects.
      float ls0=0.f, ls1=0.f;
      float w00=0.f,w01=0.f,w02=0.f,w03=0.f,w04=0.f;
      float w10=0.f,w11=0.f,w12=0.f,w13=0.f,w14=0.f;
      #pragma unroll 4
      for (int j = jlo; j < jhi; ++j) {
        float4 oj = s_o4[j]; float oe = s_o1[j];
        float s0 = (a0[0]*oj.x + a0[1]*oj.y) + ((a0[2]*oj.z + a0[3]*oj.w) + a0[4]*oe);
        float s1 = (a1[0]*oj.x + a1[1]*oj.y) + ((a1[2]*oj.z + a1[3]*oj.w) + a1[4]*oe);
        float p0 = fexp2(s0);
        float p1 = fexp2(s1);
        ls0 += p0; ls1 += p1;
        w00 += p0*oj.x; w01 += p0*oj.y; w02 += p0*oj.z; w03 += p0*oj.w; w04 += p0*oe;
        w10 += p1*oj.x; w11 += p1*oj.y; w12 += p1*oj.z; w13 += p1*oj.w; w14 += p1*oe;
      }
      // rep row: uniform 1/100 row also averages (100-nm) masked tokens,
      // each carrying the rep state itself (applied once, in group 0).
      if (rep0 && corr) {
        w00 += wext*oa[0]; w01 += wext*oa[1]; w02 += wext*oa[2];
        w03 += wext*oa[3]; w04 += wext*oa[4];
      }
      if (rep1 && corr) {
        w10 += wext*ob[0]; w11 += wext*ob[1]; w12 += wext*ob[2];
        w13 += wext*ob[3]; w14 += wext*ob[4];
      }

      // P-apply in the DENSE phase: wp = w @ P_h (unnormalized; P rows
      // shared between the two rows).  ls carried for the token pass.
      const float* Ph = mpf + 960 + ((l*NH + h)*EDIM)*8;
      float wr0[5] = {w00,w01,w02,w03,w04};
      float wr1[5] = {w10,w11,w12,w13,w14};
      float c00=0.f,c01=0.f,c02=0.f,c03=0.f,c04=0.f;
      float c10=0.f,c11=0.f,c12=0.f,c13=0.f,c14=0.f;
      #pragma unroll
      for (int e = 0; e < 5; ++e) {
        float4 pr = *(const float4*)(Ph + e*8); float p4 = Ph[e*8+4];
        float va = wr0[e], vb = wr1[e];
        c00 += va*pr.x; c01 += va*pr.y; c02 += va*pr.z; c03 += va*pr.w; c04 += va*p4;
        c10 += vb*pr.x; c11 += vb*pr.y; c12 += vb*pr.z; c13 += vb*pr.w; c14 += vb*p4;
      }
      s_w4[wg][h][i0] = make_float4(c00, c01, c02, c03);
      s_w2[wg][h][i0] = make_float2(c04, ls0);
      if (w1ok) {
        s_w4[wg][h][i1] = make_float4(c10, c11, c12, c13);
        s_w2[wg][h][i1] = make_float2(c14, ls1);
      }
    }
    __syncthreads();

    // ---- token pass: merge pre-applied head outputs, LN1, FFN, LN2 ----
    if (t <= nm) {
      int i = t;
      bool rep = (i == nm);
      float4 ov = s_o4[i]; float ov4 = s_o1[i];
      float y[5] = {ov.x, ov.y, ov.z, ov.w, ov4};
      #pragma unroll
      for (int hh = 0; hh < NH; ++hh) {
        float4 wa = s_w4[0][hh][i]; float2 wb = s_w2[0][hh][i];
        float c0 = wa.x, c1 = wa.y, c2 = wa.z, c3 = wa.w, c4 = wb.x;
        float ls = wb.y;
        if (nsplit == 2) {
          float4 wa2 = s_w4[1][hh][i]; float2 wb2 = s_w2[1][hh][i];
          c0 += wa2.x; c1 += wa2.y; c2 += wa2.z; c3 += wa2.w; c4 += wb2.x;
          ls += wb2.y;
        }
        float inv = rep ? 0.01f : frcp(ls);
        y[0] += c0*inv; y[1] += c1*inv; y[2] += c2*inv; y[3] += c3*inv; y[4] += c4*inv;
      }
      float mu = 0.2f*(y[0]+y[1]+y[2]+y[3]+y[4]);
      float var = 0.f;
      #pragma unroll
      for (int e = 0; e < 5; ++e) { float d = y[e]-mu; var += d*d; }
      float iv = frsq(var*0.2f + 1e-5f);
      float l1[5];
      #pragma unroll
      for (int e = 0; e < 5; ++e)
        l1[e] = (y[e]-mu)*iv*s_cf[90+l*5+e] + s_cf[105+l*5+e];
      float r2[5];
      #pragma unroll
      for (int e = 0; e < 5; ++e) {
        float acc = s_cf[75+l*5+e];
        #pragma unroll
        for (int f = 0; f < 5; ++f) acc += l1[f]*s_cf[l*25+e*5+f];
        acc = acc > 0.f ? acc : 0.f;
        r2[e] = acc + l1[e];
      }
      float mu2 = 0.2f*(r2[0]+r2[1]+r2[2]+r2[3]+r2[4]);
      float var2 = 0.f;
      #pragma unroll
      for (int e = 0; e < 5; ++e) { float d = r2[e]-mu2; var2 += d*d; }
      float iv2 = frsq(var2*0.2f + 1e-5f);
      float no0 = (r2[0]-mu2)*iv2*s_cf[120+l*5+0] + s_cf[135+l*5+0];
      float no1 = (r2[1]-mu2)*iv2*s_cf[120+l*5+1] + s_cf[135+l*5+1];
      float no2 = (r2[2]-mu2)*iv2*s_cf[120+l*5+2] + s_cf[135+l*5+2];
      float no3 = (r2[3]-mu2)*iv2*s_cf[120+l*5+3] + s_cf[135+l*5+3];
      float no4 = (r2[4]-mu2)*iv2*s_cf[120+l*5+4] + s_cf[135+l*5+4];
      s_o4[i] = make_float4(no0, no1, no2, no3);
      s_o1[i] = no4;
    }
    __syncthreads();
  }

  // ---- expand compacted state back to [N, E] ----
  for (int r = t; r < NTOK*EDIM; r += BLK) {
    int i = r / EDIM;
    int e = r - i*EDIM;
    int c = s_cidx[i];
    float v = (e < 4) ? ((const float*)&s_o4[c])[e] : s_o1[c];
    out[b*(NTOK*EDIM) + r] = v;
  }
}

extern "C" void kernel_launch(void* const* d_in, const int* in_sizes, int n_in,
                              void* d_out, int out_size, void* d_ws, size_t ws_size,
                              hipStream_t stream) {
  const float* x  = (const float*)d_in[0];
  const float* Wq = (const float*)d_in[1];
  const float* Wk = (const float*)d_in[2];
  const float* Wv = (const float*)d_in[3];
  const float* Wo = (const float*)d_in[4];
  const float* Wf = (const float*)d_in[5];
  const float* bf = (const float*)d_in[6];
  const float* g1 = (const float*)d_in[7];
  const float* b1 = (const float*)d_in[8];
  const float* g2 = (const float*)d_in[9];
  const float* b2 = (const float*)d_in[10];
  float* outp = (float*)d_out;
  float* mp   = (float*)d_ws;   // 1920 floats

  precompute_mp<<<24, 64, 0, stream>>>(Wq, Wk, Wv, Wo, mp);
  encoder_kernel<<<1024, BLK, 0, stream>>>(x, mp, Wf, bf, g1, b1, g2, b2, outp);
}

// Round 8
// 114.536 us; speedup vs baseline: 1.2126x; 1.0176x over previous
//
#include <hip/hip_runtime.h>
#include <math.h>

#define NTOK 100
#define EDIM 5
#define NH   4
#define NL   3
#define DD   64
#define BLK  512

// single-instruction transcendentals (1-ulp class; tolerance is 2^-7;
// HW-validated rounds 3-7)
__device__ __forceinline__ float fexp2(float x){ float r; asm("v_exp_f32 %0, %1" : "=v"(r) : "v"(x)); return r; }
__device__ __forceinline__ float frcp (float x){ float r; asm("v_rcp_f32 %0, %1" : "=v"(r) : "v"(x)); return r; }
__device__ __forceinline__ float frsq (float x){ float r; asm("v_rsq_f32 %0, %1" : "=v"(r) : "v"(x)); return r; }

// ---------------------------------------------------------------------------
// Kernel 1: fold per-head projections into 5x5 matrices.
//   M[l][h] = (1/8)*log2(e) * Wq^T Wk    (softmax uses native v_exp_f32)
//   P[l][h] = Wv^T Wo_h^T
// ws layout: float [2][NL][NH][EDIM][8]
// ---------------------------------------------------------------------------
__global__ void precompute_mp(const float* __restrict__ Wq,
                              const float* __restrict__ Wk,
                              const float* __restrict__ Wv,
                              const float* __restrict__ Wo,
                              float* __restrict__ mp) {
  const int blk = blockIdx.x;            // 24 = which(2) * l(3) * h(4)
  const int which = blk / 12;
  const int rem = blk % 12;
  const int l = rem / 4, h = rem % 4;
  const int t = threadIdx.x;             // 64 threads

  __shared__ float A[320];               // [d*5+e]
  __shared__ float Bsh[320];             // which0: [d*5+f] ; which1: [f*64+d]

  const float* wa = (which ? Wv : Wq) + (l*NH + h)*DD*EDIM;
  for (int r = t; r < 320; r += 64) A[r] = wa[r];
  if (which == 0) {
    const float* wk = Wk + (l*NH + h)*DD*EDIM;
    for (int r = t; r < 320; r += 64) Bsh[r] = wk[r];
  } else {
    for (int r = t; r < 320; r += 64) {
      int f = r >> 6, d = r & 63;
      Bsh[r] = Wo[(l*EDIM + f)*(NH*DD) + h*DD + d];
    }
  }
  __syncthreads();
  if (t < 25) {
    int e = t / 5, f = t % 5;
    float acc = 0.f;
    if (which == 0) {
      #pragma unroll 8
      for (int d = 0; d < DD; ++d) acc += A[d*5+e] * Bsh[d*5+f];
      acc *= 0.125f * 1.44269504088896340736f;   // fold log2(e) for exp2
    } else {
      #pragma unroll 8
      for (int d = 0; d < DD; ++d) acc += A[d*5+e] * Bsh[f*64+d];
    }
    mp[which*960 + ((l*NH + h)*EDIM + e)*8 + f] = acc;
  }
}

// ---------------------------------------------------------------------------
// Kernel 2: 512 threads = 8 waves per batch element -> 4 blocks/CU x 8 waves
// = 32 waves/CU (FULL occupancy, 2x round 7's 16).  Same total instruction
// count as r7, distributed thinner: ONE row per thread (natt = 4*(nm+1)),
// j-split 2 kept (408 task threads typical, j-range ~25).  r5/r6 proved
// fewer waves lose; this tests more waves with the proven LDS-broadcast
// j-loop.  All r7 lean-math retained: log2(e) folded into M, rep row via
// a=0, native v_exp/v_rcp/v_rsq, readfirstlane(nm), P-apply in the dense
// phase, LN/FFN constants in LDS.  (512,4) -> VGPR cap 128, ~40 live: no
// spill (r2's trap was (512,8) -> cap 64).
// ---------------------------------------------------------------------------
__global__ __launch_bounds__(BLK, 4) void encoder_kernel(
    const float* __restrict__ x,
    const float* __restrict__ mp,
    const float* __restrict__ Wf,
    const float* __restrict__ bfv,
    const float* __restrict__ g1,
    const float* __restrict__ b1,
    const float* __restrict__ g2,
    const float* __restrict__ b2,
    float* __restrict__ out)
{
  const int b = blockIdx.x, t = threadIdx.x;

  __shared__ float4 s_MP4[480];             // 7680 B: M then P
  __shared__ float4 s_o4[NTOK+2];           // token state [0..3]
  __shared__ float  s_o1[NTOK+2];           // token state [4]
  __shared__ float4 s_w4[2][NH][NTOK+2];    // wp[0..3] per (jgroup,h,i)
  __shared__ float2 s_w2[2][NH][NTOK+2];    // {wp[4], ls}
  __shared__ float  s_cf[152];              // Wf | bf | g1 | b1 | g2 | b2
  __shared__ int    s_cidx[NTOK];
  __shared__ unsigned long long s_bal[2];

  const float* mpf = (const float*)s_MP4;

  for (int r = t; r < 480; r += BLK) s_MP4[r] = ((const float4*)mp)[r];
  for (int r = t; r < 150; r += BLK) {
    float v;
    if      (r <  75) v = Wf[r];
    else if (r <  90) v = bfv[r-75];
    else if (r < 105) v = g1[r-90];
    else if (r < 120) v = b1[r-105];
    else if (r < 135) v = g2[r-120];
    else              v = b2[r-135];
    s_cf[r] = v;
  }

  // ---- setup: mask + ballot-based compaction ----
  float k0=0.f, k1=0.f, k2=0.f, msk=0.f;
  if (t < NTOK) {
    k0 = x[b*300 + 3*t];
    k1 = x[b*300 + 3*t + 1];
    k2 = x[b*300 + 3*t + 2];
    msk = (k2 > 0.f) ? 1.f : 0.f;
  }
  unsigned long long bal = __ballot(t < NTOK && msk != 0.f);
  if (t == 0)  s_bal[0] = bal;
  if (t == 64) s_bal[1] = bal;
  __syncthreads();
  const unsigned long long bw0 = s_bal[0], bw1 = s_bal[1];
  // readfirstlane: nm (and all derived bounds) provably uniform
  const int nm = __builtin_amdgcn_readfirstlane(__popcll(bw0) + __popcll(bw1));
  if (t < NTOK) {
    int lane = t & 63;
    unsigned long long lm = (lane == 0) ? 0ull : ((1ull << lane) - 1ull);
    int pre = (t < 64) ? __popcll(bw0 & lm) : (__popcll(bw0) + __popcll(bw1 & lm));
    if (msk != 0.f) {
      s_o4[pre] = make_float4(k0, k1, k2, __sinf((float)t));
      s_o1[pre] = __cosf((float)t);
      s_cidx[t] = pre;
    } else {
      s_cidx[t] = nm;
    }
  }
  if (t == 0) {
    s_o4[nm]   = make_float4(0.f,0.f,0.f,0.f); s_o1[nm]   = 0.f;  // rep token
    s_o4[nm+1] = make_float4(0.f,0.f,0.f,0.f); s_o1[nm+1] = 0.f;
  }
  __syncthreads();

  // ---- static task mapping: 1 row/thread, adaptive j-split ----
  const int rowsN = nm + 1;                 // rows incl. rep token
  const int natt  = NH * rowsN;             // threads per j-group (<=404)
  const int nsplit = (2*natt <= BLK) ? 2 : 1;   // nm<=63 -> 2 (typical)
  const bool task = (t < natt*nsplit);
  int h = 0, i0 = 0, jlo = 0, jhi = 0;
  bool rep0 = false, corr = false;
  if (task) {
    int g  = t / natt;
    int tt = t - g*natt;
    h = tt / rowsN; i0 = tt - h*rowsN;
    rep0 = (i0 == nm);
    corr = (g == 0);                        // rep-correction applied once
    int jmid = nm >> 1;
    if (nsplit == 2) { jlo = g ? jmid : 0; jhi = g ? nm : jmid; }
    else             { jlo = 0; jhi = nm; }
  }
  const int wg = task ? (t / natt) : 0;
  const float wext = (float)(NTOK - nm);

  for (int l = 0; l < NL; ++l) {
    if (task) {
      // a = o @ M_h for this thread's row
      const float* Mh = mpf + ((l*NH + h)*EDIM)*8;
      float4 oA = s_o4[i0];  float oA4 = s_o1[i0];
      float oa[5] = {oA.x, oA.y, oA.z, oA.w, oA4};
      float a0[5];
      #pragma unroll
      for (int f = 0; f < 5; ++f) a0[f] = 0.f;
      #pragma unroll
      for (int e = 0; e < 5; ++e) {
        float4 mr = *(const float4*)(Mh + e*8); float m4 = Mh[e*8+4];
        float va = oa[e];
        a0[0] += va*mr.x; a0[1] += va*mr.y; a0[2] += va*mr.z;
        a0[3] += va*mr.w; a0[4] += va*m4;
      }
      if (rep0) { a0[0]=0.f; a0[1]=0.f; a0[2]=0.f; a0[3]=0.f; a0[4]=0.f; } // exp2(0)=1

      // attention j-loop: LDS broadcast reads, 1-row body, native exp2
      float ls0=0.f;
      float w00=0.f,w01=0.f,w02=0.f,w03=0.f,w04=0.f;
      #pragma unroll 8
      for (int j = jlo; j < jhi; ++j) {
        float4 oj = s_o4[j]; float oe = s_o1[j];
        float s0 = (a0[0]*oj.x + a0[1]*oj.y) + ((a0[2]*oj.z + a0[3]*oj.w) + a0[4]*oe);
        float p0 = fexp2(s0);
        ls0 += p0;
        w00 += p0*oj.x; w01 += p0*oj.y; w02 += p0*oj.z; w03 += p0*oj.w; w04 += p0*oe;
      }
      // rep row: uniform 1/100 row also averages (100-nm) masked tokens,
      // each carrying the rep state itself (applied once, in group 0).
      if (rep0 && corr) {
        w00 += wext*oa[0]; w01 += wext*oa[1]; w02 += wext*oa[2];
        w03 += wext*oa[3]; w04 += wext*oa[4];
      }

      // P-apply in the DENSE phase: wp = w @ P_h (unnormalized; ls carried)
      const float* Ph = mpf + 960 + ((l*NH + h)*EDIM)*8;
      float wr0[5] = {w00,w01,w02,w03,w04};
      float c00=0.f,c01=0.f,c02=0.f,c03=0.f,c04=0.f;
      #pragma unroll
      for (int e = 0; e < 5; ++e) {
        float4 pr = *(const float4*)(Ph + e*8); float p4 = Ph[e*8+4];
        float va = wr0[e];
        c00 += va*pr.x; c01 += va*pr.y; c02 += va*pr.z; c03 += va*pr.w; c04 += va*p4;
      }
      s_w4[wg][h][i0] = make_float4(c00, c01, c02, c03);
      s_w2[wg][h][i0] = make_float2(c04, ls0);
    }
    __syncthreads();

    // ---- token pass: merge pre-applied head outputs, LN1, FFN, LN2 ----
    if (t <= nm) {
      int i = t;
      bool rep = (i == nm);
      float4 ov = s_o4[i]; float ov4 = s_o1[i];
      float y[5] = {ov.x, ov.y, ov.z, ov.w, ov4};
      #pragma unroll
      for (int hh = 0; hh < NH; ++hh) {
        float4 wa = s_w4[0][hh][i]; float2 wb = s_w2[0][hh][i];
        float c0 = wa.x, c1 = wa.y, c2 = wa.z, c3 = wa.w, c4 = wb.x;
        float ls = wb.y;
        if (nsplit == 2) {
          float4 wa2 = s_w4[1][hh][i]; float2 wb2 = s_w2[1][hh][i];
          c0 += wa2.x; c1 += wa2.y; c2 += wa2.z; c3 += wa2.w; c4 += wb2.x;
          ls += wb2.y;
        }
        float inv = rep ? 0.01f : frcp(ls);
        y[0] += c0*inv; y[1] += c1*inv; y[2] += c2*inv; y[3] += c3*inv; y[4] += c4*inv;
      }
      float mu = 0.2f*(y[0]+y[1]+y[2]+y[3]+y[4]);
      float var = 0.f;
      #pragma unroll
      for (int e = 0; e < 5; ++e) { float d = y[e]-mu; var += d*d; }
      float iv = frsq(var*0.2f + 1e-5f);
      float l1[5];
      #pragma unroll
      for (int e = 0; e < 5; ++e)
        l1[e] = (y[e]-mu)*iv*s_cf[90+l*5+e] + s_cf[105+l*5+e];
      float r2[5];
      #pragma unroll
      for (int e = 0; e < 5; ++e) {
        float acc = s_cf[75+l*5+e];
        #pragma unroll
        for (int f = 0; f < 5; ++f) acc += l1[f]*s_cf[l*25+e*5+f];
        acc = acc > 0.f ? acc : 0.f;
        r2[e] = acc + l1[e];
      }
      float mu2 = 0.2f*(r2[0]+r2[1]+r2[2]+r2[3]+r2[4]);
      float var2 = 0.f;
      #pragma unroll
      for (int e = 0; e < 5; ++e) { float d = r2[e]-mu2; var2 += d*d; }
      float iv2 = frsq(var2*0.2f + 1e-5f);
      float no0 = (r2[0]-mu2)*iv2*s_cf[120+l*5+0] + s_cf[135+l*5+0];
      float no1 = (r2[1]-mu2)*iv2*s_cf[120+l*5+1] + s_cf[135+l*5+1];
      float no2 = (r2[2]-mu2)*iv2*s_cf[120+l*5+2] + s_cf[135+l*5+2];
      float no3 = (r2[3]-mu2)*iv2*s_cf[120+l*5+3] + s_cf[135+l*5+3];
      float no4 = (r2[4]-mu2)*iv2*s_cf[120+l*5+4] + s_cf[135+l*5+4];
      s_o4[i] = make_float4(no0, no1, no2, no3);
      s_o1[i] = no4;
    }
    __syncthreads();
  }

  // ---- expand compacted state back to [N, E] ----
  for (int r = t; r < NTOK*EDIM; r += BLK) {
    int i = r / EDIM;
    int e = r - i*EDIM;
    int c = s_cidx[i];
    float v = (e < 4) ? ((const float*)&s_o4[c])[e] : s_o1[c];
    out[b*(NTOK*EDIM) + r] = v;
  }
}

extern "C" void kernel_launch(void* const* d_in, const int* in_sizes, int n_in,
                              void* d_out, int out_size, void* d_ws, size_t ws_size,
                              hipStream_t stream) {
  const float* x  = (const float*)d_in[0];
  const float* Wq = (const float*)d_in[1];
  const float* Wk = (const float*)d_in[2];
  const float* Wv = (const float*)d_in[3];
  const float* Wo = (const float*)d_in[4];
  const float* Wf = (const float*)d_in[5];
  const float* bf = (const float*)d_in[6];
  const float* g1 = (const float*)d_in[7];
  const float* b1 = (const float*)d_in[8];
  const float* g2 = (const float*)d_in[9];
  const float* b2 = (const float*)d_in[10];
  float* outp = (float*)d_out;
  float* mp   = (float*)d_ws;   // 1920 floats

  precompute_mp<<<24, 64, 0, stream>>>(Wq, Wk, Wv, Wo, mp);
  encoder_kernel<<<1024, BLK, 0, stream>>>(x, mp, Wf, bf, g1, b1, g2, b2, outp);
}

// Round 9
// 114.115 us; speedup vs baseline: 1.2171x; 1.0037x over previous
//
#include <hip/hip_runtime.h>
#include <math.h>

#define NTOK 100
#define EDIM 5
#define NH   4
#define NL   3
#define DD   64
#define BLK  512

// single-instruction transcendentals (1-ulp class; tolerance is 2^-7;
// HW-validated rounds 3-8)
__device__ __forceinline__ float fexp2(float x){ float r; asm("v_exp_f32 %0, %1" : "=v"(r) : "v"(x)); return r; }
__device__ __forceinline__ float frcp (float x){ float r; asm("v_rcp_f32 %0, %1" : "=v"(r) : "v"(x)); return r; }
__device__ __forceinline__ float frsq (float x){ float r; asm("v_rsq_f32 %0, %1" : "=v"(r) : "v"(x)); return r; }

// ---------------------------------------------------------------------------
// Kernel 1: fold per-head projections into 5x5 matrices.
//   M[l][h] = (1/8)*log2(e) * Wq^T Wk    (softmax uses native v_exp_f32)
//   P[l][h] = Wv^T Wo_h^T
// ws layout: float [2][NL][NH][EDIM][8]
// ---------------------------------------------------------------------------
__global__ void precompute_mp(const float* __restrict__ Wq,
                              const float* __restrict__ Wk,
                              const float* __restrict__ Wv,
                              const float* __restrict__ Wo,
                              float* __restrict__ mp) {
  const int blk = blockIdx.x;            // 24 = which(2) * l(3) * h(4)
  const int which = blk / 12;
  const int rem = blk % 12;
  const int l = rem / 4, h = rem % 4;
  const int t = threadIdx.x;             // 64 threads

  __shared__ float A[320];               // [d*5+e]
  __shared__ float Bsh[320];             // which0: [d*5+f] ; which1: [f*64+d]

  const float* wa = (which ? Wv : Wq) + (l*NH + h)*DD*EDIM;
  for (int r = t; r < 320; r += 64) A[r] = wa[r];
  if (which == 0) {
    const float* wk = Wk + (l*NH + h)*DD*EDIM;
    for (int r = t; r < 320; r += 64) Bsh[r] = wk[r];
  } else {
    for (int r = t; r < 320; r += 64) {
      int f = r >> 6, d = r & 63;
      Bsh[r] = Wo[(l*EDIM + f)*(NH*DD) + h*DD + d];
    }
  }
  __syncthreads();
  if (t < 25) {
    int e = t / 5, f = t % 5;
    float acc = 0.f;
    if (which == 0) {
      #pragma unroll 8
      for (int d = 0; d < DD; ++d) acc += A[d*5+e] * Bsh[d*5+f];
      acc *= 0.125f * 1.44269504088896340736f;   // fold log2(e) for exp2
    } else {
      #pragma unroll 8
      for (int d = 0; d < DD; ++d) acc += A[d*5+e] * Bsh[f*64+d];
    }
    mp[which*960 + ((l*NH + h)*EDIM + e)*8 + f] = acc;
  }
}

// ---------------------------------------------------------------------------
// Kernel 2: r8's structure (512 thr, 1 row/thread, j-split 2, LDS-broadcast
// j-loop, lean math) with ONE deliberate change: __launch_bounds__(512, 8)
// -> VGPR cap 64 -> TRUE 8 waves/EU (32 waves/CU).  Occupancy re-derivation
// showed r7/r8 both actually ran 16 waves/CU (r8's (512,4) = cap 128; the
// unroll-8 j-loop exceeded 64 VGPRs), so the TLP experiment never ran.
// unroll dropped 8 -> 4 to cut in-flight register demand (~45-55 live;
// r2's cap-64 spill was a ~90-live 2-row readlane body, not this).
// Spill tripwire: WRITE_SIZE must stay ~2 MB.
// ---------------------------------------------------------------------------
__global__ __launch_bounds__(BLK, 8) void encoder_kernel(
    const float* __restrict__ x,
    const float* __restrict__ mp,
    const float* __restrict__ Wf,
    const float* __restrict__ bfv,
    const float* __restrict__ g1,
    const float* __restrict__ b1,
    const float* __restrict__ g2,
    const float* __restrict__ b2,
    float* __restrict__ out)
{
  const int b = blockIdx.x, t = threadIdx.x;

  __shared__ float4 s_MP4[480];             // 7680 B: M then P
  __shared__ float4 s_o4[NTOK+2];           // token state [0..3]
  __shared__ float  s_o1[NTOK+2];           // token state [4]
  __shared__ float4 s_w4[2][NH][NTOK+2];    // wp[0..3] per (jgroup,h,i)
  __shared__ float2 s_w2[2][NH][NTOK+2];    // {wp[4], ls}
  __shared__ float  s_cf[152];              // Wf | bf | g1 | b1 | g2 | b2
  __shared__ int    s_cidx[NTOK];
  __shared__ unsigned long long s_bal[2];

  const float* mpf = (const float*)s_MP4;

  for (int r = t; r < 480; r += BLK) s_MP4[r] = ((const float4*)mp)[r];
  for (int r = t; r < 150; r += BLK) {
    float v;
    if      (r <  75) v = Wf[r];
    else if (r <  90) v = bfv[r-75];
    else if (r < 105) v = g1[r-90];
    else if (r < 120) v = b1[r-105];
    else if (r < 135) v = g2[r-120];
    else              v = b2[r-135];
    s_cf[r] = v;
  }

  // ---- setup: mask + ballot-based compaction ----
  float k0=0.f, k1=0.f, k2=0.f, msk=0.f;
  if (t < NTOK) {
    k0 = x[b*300 + 3*t];
    k1 = x[b*300 + 3*t + 1];
    k2 = x[b*300 + 3*t + 2];
    msk = (k2 > 0.f) ? 1.f : 0.f;
  }
  unsigned long long bal = __ballot(t < NTOK && msk != 0.f);
  if (t == 0)  s_bal[0] = bal;
  if (t == 64) s_bal[1] = bal;
  __syncthreads();
  const unsigned long long bw0 = s_bal[0], bw1 = s_bal[1];
  // readfirstlane: nm (and all derived bounds) provably uniform
  const int nm = __builtin_amdgcn_readfirstlane(__popcll(bw0) + __popcll(bw1));
  if (t < NTOK) {
    int lane = t & 63;
    unsigned long long lm = (lane == 0) ? 0ull : ((1ull << lane) - 1ull);
    int pre = (t < 64) ? __popcll(bw0 & lm) : (__popcll(bw0) + __popcll(bw1 & lm));
    if (msk != 0.f) {
      s_o4[pre] = make_float4(k0, k1, k2, __sinf((float)t));
      s_o1[pre] = __cosf((float)t);
      s_cidx[t] = pre;
    } else {
      s_cidx[t] = nm;
    }
  }
  if (t == 0) {
    s_o4[nm]   = make_float4(0.f,0.f,0.f,0.f); s_o1[nm]   = 0.f;  // rep token
    s_o4[nm+1] = make_float4(0.f,0.f,0.f,0.f); s_o1[nm+1] = 0.f;
  }
  __syncthreads();

  // ---- static task mapping: 1 row/thread, adaptive j-split ----
  const int rowsN = nm + 1;                 // rows incl. rep token
  const int natt  = NH * rowsN;             // threads per j-group (<=404)
  const int nsplit = (2*natt <= BLK) ? 2 : 1;   // nm<=63 -> 2 (typical)
  const bool task = (t < natt*nsplit);
  int h = 0, i0 = 0, jlo = 0, jhi = 0;
  bool rep0 = false, corr = false;
  if (task) {
    int g  = t / natt;
    int tt = t - g*natt;
    h = tt / rowsN; i0 = tt - h*rowsN;
    rep0 = (i0 == nm);
    corr = (g == 0);                        // rep-correction applied once
    int jmid = nm >> 1;
    if (nsplit == 2) { jlo = g ? jmid : 0; jhi = g ? nm : jmid; }
    else             { jlo = 0; jhi = nm; }
  }
  const int wg = task ? (t / natt) : 0;
  const float wext = (float)(NTOK - nm);

  for (int l = 0; l < NL; ++l) {
    if (task) {
      // a = o @ M_h for this thread's row
      const float* Mh = mpf + ((l*NH + h)*EDIM)*8;
      float4 oA = s_o4[i0];  float oA4 = s_o1[i0];
      float oa[5] = {oA.x, oA.y, oA.z, oA.w, oA4};
      float a0[5];
      #pragma unroll
      for (int f = 0; f < 5; ++f) a0[f] = 0.f;
      #pragma unroll
      for (int e = 0; e < 5; ++e) {
        float4 mr = *(const float4*)(Mh + e*8); float m4 = Mh[e*8+4];
        float va = oa[e];
        a0[0] += va*mr.x; a0[1] += va*mr.y; a0[2] += va*mr.z;
        a0[3] += va*mr.w; a0[4] += va*m4;
      }
      if (rep0) { a0[0]=0.f; a0[1]=0.f; a0[2]=0.f; a0[3]=0.f; a0[4]=0.f; } // exp2(0)=1

      // attention j-loop: LDS broadcast reads, 1-row body, native exp2.
      // unroll 4 (not 8): caps in-flight oj registers so the body fits the
      // 64-VGPR budget of 8 waves/EU; latency hiding shifts to TLP.
      float ls0=0.f;
      float w00=0.f,w01=0.f,w02=0.f,w03=0.f,w04=0.f;
      #pragma unroll 4
      for (int j = jlo; j < jhi; ++j) {
        float4 oj = s_o4[j]; float oe = s_o1[j];
        float s0 = (a0[0]*oj.x + a0[1]*oj.y) + ((a0[2]*oj.z + a0[3]*oj.w) + a0[4]*oe);
        float p0 = fexp2(s0);
        ls0 += p0;
        w00 += p0*oj.x; w01 += p0*oj.y; w02 += p0*oj.z; w03 += p0*oj.w; w04 += p0*oe;
      }
      // rep row: uniform 1/100 row also averages (100-nm) masked tokens,
      // each carrying the rep state itself (applied once, in group 0).
      if (rep0 && corr) {
        w00 += wext*oa[0]; w01 += wext*oa[1]; w02 += wext*oa[2];
        w03 += wext*oa[3]; w04 += wext*oa[4];
      }

      // P-apply in the DENSE phase: wp = w @ P_h (unnormalized; ls carried)
      const float* Ph = mpf + 960 + ((l*NH + h)*EDIM)*8;
      float wr0[5] = {w00,w01,w02,w03,w04};
      float c00=0.f,c01=0.f,c02=0.f,c03=0.f,c04=0.f;
      #pragma unroll
      for (int e = 0; e < 5; ++e) {
        float4 pr = *(const float4*)(Ph + e*8); float p4 = Ph[e*8+4];
        float va = wr0[e];
        c00 += va*pr.x; c01 += va*pr.y; c02 += va*pr.z; c03 += va*pr.w; c04 += va*p4;
      }
      s_w4[wg][h][i0] = make_float4(c00, c01, c02, c03);
      s_w2[wg][h][i0] = make_float2(c04, ls0);
    }
    __syncthreads();

    // ---- token pass: merge pre-applied head outputs, LN1, FFN, LN2 ----
    if (t <= nm) {
      int i = t;
      bool rep = (i == nm);
      float4 ov = s_o4[i]; float ov4 = s_o1[i];
      float y[5] = {ov.x, ov.y, ov.z, ov.w, ov4};
      #pragma unroll
      for (int hh = 0; hh < NH; ++hh) {
        float4 wa = s_w4[0][hh][i]; float2 wb = s_w2[0][hh][i];
        float c0 = wa.x, c1 = wa.y, c2 = wa.z, c3 = wa.w, c4 = wb.x;
        float ls = wb.y;
        if (nsplit == 2) {
          float4 wa2 = s_w4[1][hh][i]; float2 wb2 = s_w2[1][hh][i];
          c0 += wa2.x; c1 += wa2.y; c2 += wa2.z; c3 += wa2.w; c4 += wb2.x;
          ls += wb2.y;
        }
        float inv = rep ? 0.01f : frcp(ls);
        y[0] += c0*inv; y[1] += c1*inv; y[2] += c2*inv; y[3] += c3*inv; y[4] += c4*inv;
      }
      float mu = 0.2f*(y[0]+y[1]+y[2]+y[3]+y[4]);
      float var = 0.f;
      #pragma unroll
      for (int e = 0; e < 5; ++e) { float d = y[e]-mu; var += d*d; }
      float iv = frsq(var*0.2f + 1e-5f);
      float l1[5];
      #pragma unroll
      for (int e = 0; e < 5; ++e)
        l1[e] = (y[e]-mu)*iv*s_cf[90+l*5+e] + s_cf[105+l*5+e];
      float r2[5];
      #pragma unroll
      for (int e = 0; e < 5; ++e) {
        float acc = s_cf[75+l*5+e];
        #pragma unroll
        for (int f = 0; f < 5; ++f) acc += l1[f]*s_cf[l*25+e*5+f];
        acc = acc > 0.f ? acc : 0.f;
        r2[e] = acc + l1[e];
      }
      float mu2 = 0.2f*(r2[0]+r2[1]+r2[2]+r2[3]+r2[4]);
      float var2 = 0.f;
      #pragma unroll
      for (int e = 0; e < 5; ++e) { float d = r2[e]-mu2; var2 += d*d; }
      float iv2 = frsq(var2*0.2f + 1e-5f);
      float no0 = (r2[0]-mu2)*iv2*s_cf[120+l*5+0] + s_cf[135+l*5+0];
      float no1 = (r2[1]-mu2)*iv2*s_cf[120+l*5+1] + s_cf[135+l*5+1];
      float no2 = (r2[2]-mu2)*iv2*s_cf[120+l*5+2] + s_cf[135+l*5+2];
      float no3 = (r2[3]-mu2)*iv2*s_cf[120+l*5+3] + s_cf[135+l*5+3];
      float no4 = (r2[4]-mu2)*iv2*s_cf[120+l*5+4] + s_cf[135+l*5+4];
      s_o4[i] = make_float4(no0, no1, no2, no3);
      s_o1[i] = no4;
    }
    __syncthreads();
  }

  // ---- expand compacted state back to [N, E] ----
  for (int r = t; r < NTOK*EDIM; r += BLK) {
    int i = r / EDIM;
    int e = r - i*EDIM;
    int c = s_cidx[i];
    float v = (e < 4) ? ((const float*)&s_o4[c])[e] : s_o1[c];
    out[b*(NTOK*EDIM) + r] = v;
  }
}

extern "C" void kernel_launch(void* const* d_in, const int* in_sizes, int n_in,
                              void* d_out, int out_size, void* d_ws, size_t ws_size,
                              hipStream_t stream) {
  const float* x  = (const float*)d_in[0];
  const float* Wq = (const float*)d_in[1];
  const float* Wk = (const float*)d_in[2];
  const float* Wv = (const float*)d_in[3];
  const float* Wo = (const float*)d_in[4];
  const float* Wf = (const float*)d_in[5];
  const float* bf = (const float*)d_in[6];
  const float* g1 = (const float*)d_in[7];
  const float* b1 = (const float*)d_in[8];
  const float* g2 = (const float*)d_in[9];
  const float* b2 = (const float*)d_in[10];
  float* outp = (float*)d_out;
  float* mp   = (float*)d_ws;   // 1920 floats

  precompute_mp<<<24, 64, 0, stream>>>(Wq, Wk, Wv, Wo, mp);
  encoder_kernel<<<1024, BLK, 0, stream>>>(x, mp, Wf, bf, g1, b1, g2, b2, outp);
}